// Round 4
// baseline (133.537 us; speedup 1.0000x reference)
//
#include <hip/hip_runtime.h>

typedef _Float16 h2 __attribute__((ext_vector_type(2)));
typedef unsigned int u32;

// Workspace layout (bytes); total 2 MB.
#define OFF_XP   0u         // half2[64][1024]   x, k-pairs packed, [kk][r]
#define OFF_YP   0x40000u   // half2[64][1024]   y
#define OFF_W1XP 0x80000u   // half2[64][256]    W1[:128] k-pair packed [kk][h]
#define OFF_W1YP 0x90000u   // half2[64][256]    W1[128:]
#define OFF_W2H  0xA0000u   // half2[128]        W2 h-pair packed
#define OFF_A2   0x100000u  // half2 TILED: [32 slab][32 row][128 hh]  (pre_x)
#define OFF_C2   0x180000u  // same tiling      (pre_y + b1)

__device__ __forceinline__ u32 pack2(float a, float b) {
  h2 v; v.x = (_Float16)a; v.y = (_Float16)b;
  return __builtin_bit_cast(u32, v);
}
__device__ __forceinline__ h2 as_h2(u32 u) { return __builtin_bit_cast(h2, u); }

__device__ __forceinline__ float fdot2(h2 a, h2 b, float c) {
#if __has_builtin(__builtin_amdgcn_fdot2)
  return __builtin_amdgcn_fdot2(a, b, c, false);
#else
  return (float)a.x * (float)b.x + (float)a.y * (float)b.y + c;
#endif
}
__device__ __forceinline__ h2 relu2(h2 t) {
  h2 z; z.x = (_Float16)0.0f; z.y = (_Float16)0.0f;
  return __builtin_elementwise_max(t, z);  // v_pk_max_f16
}

// K0: transpose/pack x,y -> [kk][r] half2; W1 -> [kk][h]; W2 -> h-pairs. Zeroes out.
__global__ void k0_pack(const float* __restrict__ x, const float* __restrict__ y,
                        const float* __restrict__ W1, const float* __restrict__ W2,
                        u32* __restrict__ wsu, float* __restrict__ out) {
  const int b = blockIdx.x, tid = threadIdx.x;
  if (b < 128) {
    if (b == 0) {
      if (tid == 0) out[0] = 0.0f;  // atomic accumulator init (d_out is poisoned)
      if (tid < 128) wsu[(OFF_W2H >> 2) + tid] = pack2(W2[2 * tid], W2[2 * tid + 1]);
    }
    const float* src = (b < 64) ? x : y;
    u32* dst = wsu + ((b < 64) ? (OFF_XP >> 2) : (OFF_YP >> 2));
    const int bb = b & 63, kt = bb & 3, rt = bb >> 2;  // 32-k tile, 64-r tile
    __shared__ float sT[64][33];                        // +1 pad: conflict-free
    const int kl = tid & 31, rg = tid >> 5;
#pragma unroll
    for (int p = 0; p < 8; ++p) {
      const int r = p * 8 + rg;
      sT[r][kl] = src[(rt * 64 + r) * 128 + kt * 32 + kl];  // coalesced
    }
    __syncthreads();
    const int rl = tid & 63, kg = tid >> 6;
#pragma unroll
    for (int q = 0; q < 4; ++q) {
      const int kkl = q * 4 + kg;  // 0..15
      dst[(kt * 16 + kkl) * 1024 + rt * 64 + rl] =
          pack2(sT[rl][2 * kkl], sT[rl][2 * kkl + 1]);      // coalesced
    }
  } else {
    const int kk = b - 128, h = tid;  // W1 rows are already h-contiguous
    wsu[(OFF_W1XP >> 2) + kk * 256 + h] =
        pack2(W1[(2 * kk) * 256 + h], W1[(2 * kk + 1) * 256 + h]);
    wsu[(OFF_W1YP >> 2) + kk * 256 + h] =
        pack2(W1[(128 + 2 * kk) * 256 + h], W1[(129 + 2 * kk) * 256 + h]);
  }
}

// K1: pre_x -> a2t, pre_y + b1 -> c2t.  512 blocks (2 waves/SIMD), depth-8 ring.
// Output layout (u32 = half2 h-pair): idx = rt*4096 + r*128 + hh.
__global__ __launch_bounds__(256) void k1_pre(u32* __restrict__ wsu,
                                              const float* __restrict__ b1) {
  const int b = blockIdx.x, tid = threadIdx.x;
  const int mat = b >> 8;                       // 0: x->a2t, 1: y->c2t
  const int bb = b & 255, ht = bb & 7, rt = bb >> 3;  // 32-h tile, 32-r tile
  const int tx = tid & 31, ty = tid >> 5;       // r lane, h group
  const int h0 = ht * 32 + ty * 4;              // 4 h / thread, 1 r / thread
  const u32* xp  = wsu + (mat ? (OFF_YP >> 2) : (OFF_XP >> 2)) + rt * 32 + tx;
  const u32* w1p = wsu + (mat ? (OFF_W1YP >> 2) : (OFF_W1XP >> 2)) + h0;
  u32* dst = wsu + (mat ? (OFF_C2 >> 2) : (OFF_A2 >> 2)) + rt * 4096 + tx * 128;

  float acc[4];
  if (mat) {
    const float4 bv = *(const float4*)(b1 + h0);
    acc[0] = bv.x; acc[1] = bv.y; acc[2] = bv.z; acc[3] = bv.w;
  } else {
    acc[0] = acc[1] = acc[2] = acc[3] = 0.0f;
  }

  u32 XR[8]; uint4 WR[8];                       // depth-8 prefetch ring
#pragma unroll
  for (int s = 0; s < 8; ++s) {
    XR[s] = xp[s * 1024];
    WR[s] = *(const uint4*)(w1p + s * 256);
  }
#pragma unroll 8
  for (int kk = 0; kk < 56; ++kk) {             // main: consume + prefetch kk+8
    const int s = kk & 7;
    const h2 xr = as_h2(XR[s]); const uint4 wv = WR[s];
    XR[s] = xp[(kk + 8) * 1024];
    WR[s] = *(const uint4*)(w1p + (kk + 8) * 256);
    acc[0] = fdot2(xr, as_h2(wv.x), acc[0]);
    acc[1] = fdot2(xr, as_h2(wv.y), acc[1]);
    acc[2] = fdot2(xr, as_h2(wv.z), acc[2]);
    acc[3] = fdot2(xr, as_h2(wv.w), acc[3]);
  }
#pragma unroll
  for (int kk = 56; kk < 64; ++kk) {            // tail: consume only
    const int s = kk & 7;
    const h2 xr = as_h2(XR[s]); const uint4 wv = WR[s];
    acc[0] = fdot2(xr, as_h2(wv.x), acc[0]);
    acc[1] = fdot2(xr, as_h2(wv.y), acc[1]);
    acc[2] = fdot2(xr, as_h2(wv.z), acc[2]);
    acc[3] = fdot2(xr, as_h2(wv.w), acc[3]);
  }
  const int hh0 = ht * 16 + ty * 2;             // even -> 8B-aligned uint2 store
  uint2 sv;
  sv.x = pack2(acc[0], acc[1]);
  sv.y = pack2(acc[2], acc[3]);
  *(uint2*)(dst + hh0) = sv;
}

// K2: main N^2 kernel. 256 blocks of 64x64 rows; 4x4 rows/thread (16 acc).
// LDS reads/FLOP halved vs R3 (8 ds_read_b128 per 4-hh group vs 192 VALU instr
// -> LDS pipe ~384 cyc/CU/group == VALU ~384 cyc/SIMD/group, balanced).
// W2 read via uniform index -> s_load (K$), zero LDS cost.
__global__ __launch_bounds__(256) void k2_main(const u32* __restrict__ wsu,
                                               const float* __restrict__ B2,
                                               float* __restrict__ out) {
  const int bi = blockIdx.x >> 4, bj = blockIdx.x & 15;
  const int tid = threadIdx.x;
  const int tx = tid & 15, ty = tid >> 4;       // j-group, i-group (4 rows each)

  __shared__ uint4 sA4[64 * 32];                // [row][quad ^ ((row>>2)&7)]
  __shared__ uint4 sC4[64 * 32];
  __shared__ float sred[4];

  {                                             // stage 64KB once (L2-resident src)
    const u32* gA = wsu + (OFF_A2 >> 2) + bj * 8192;
    const u32* gC = wsu + (OFF_C2 >> 2) + bi * 8192;
    const int j = tid >> 2, t4 = tid & 3, sw = (j >> 2) & 7;
#pragma unroll
    for (int m = 0; m < 8; ++m) {
      const int q = t4 + 4 * m;
      sA4[j * 32 + (q ^ sw)] = *(const uint4*)(gA + j * 128 + q * 4);
      sC4[j * 32 + (q ^ sw)] = *(const uint4*)(gC + j * 128 + q * 4);
    }
  }
  __syncthreads();

  const uint4* pA = sA4 + (tx * 4) * 32;        // rows 4tx..4tx+3
  const uint4* pC = sC4 + (ty * 4) * 32;        // rows 4ty..4ty+3
  const uint4* pW = (const uint4*)(wsu + (OFF_W2H >> 2));  // uniform -> s_load
  const int swzA = tx & 7, swzC = ty & 7;

  float acc[16];
#pragma unroll
  for (int p = 0; p < 16; ++p) acc[p] = 0.0f;

  uint4 Ar[2][4], Cr[2][4];                     // depth-2 group ring
#pragma unroll
  for (int r = 0; r < 4; ++r) {
    Ar[0][r] = pA[r * 32 + swzA];               // g=0: 0^swz = swz
    Cr[0][r] = pC[r * 32 + swzC];
  }
#pragma unroll 4
  for (int g = 0; g < 32; ++g) {
    const int s = g & 1, ns = s ^ 1;
    if (g < 31) {
      const int g1 = g + 1;
#pragma unroll
      for (int r = 0; r < 4; ++r) {
        Ar[ns][r] = pA[r * 32 + (g1 ^ swzA)];
        Cr[ns][r] = pC[r * 32 + (g1 ^ swzC)];
      }
    }
    const uint4 wv = pW[g];
    const u32 ww[4] = {wv.x, wv.y, wv.z, wv.w};
    u32 aa[4][4], cc[4][4];
#pragma unroll
    for (int r = 0; r < 4; ++r) {
      aa[r][0] = Ar[s][r].x; aa[r][1] = Ar[s][r].y;
      aa[r][2] = Ar[s][r].z; aa[r][3] = Ar[s][r].w;
      cc[r][0] = Cr[s][r].x; cc[r][1] = Cr[s][r].y;
      cc[r][2] = Cr[s][r].z; cc[r][3] = Cr[s][r].w;
    }
#pragma unroll
    for (int m = 0; m < 4; ++m) {               // 4 hh in this group
      const h2 w = as_h2(ww[m]);
#pragma unroll
      for (int ii = 0; ii < 4; ++ii) {
        const h2 ci = as_h2(cc[ii][m]);
#pragma unroll
        for (int jj = 0; jj < 4; ++jj) {
          acc[ii * 4 + jj] = fdot2(relu2(as_h2(aa[jj][m]) + ci), w, acc[ii * 4 + jj]);
        }
      }
    }
  }

  // result = (1/n) sum_i (T1_ii + 1) - (1/n^2) sum_ij exp(T1_ij),
  // T1_ij = d_ij + b2 - 1.  acc[] holds d_ij.
  const float b2 = B2[0];
  float val = 0.0f;
#pragma unroll
  for (int p = 0; p < 16; ++p) val += __expf(acc[p] + (b2 - 1.0f));
  val *= -1.0f / 1048576.0f;
  if (bi == bj && tx == ty) {                   // diag: local i==j -> acc[c*5]
    float d = 0.0f;
#pragma unroll
    for (int c = 0; c < 4; ++c) d += acc[c * 5];
    val += (d + 4.0f * b2) * (1.0f / 1024.0f);
  }
#pragma unroll
  for (int off = 32; off > 0; off >>= 1) val += __shfl_down(val, off, 64);
  if ((tid & 63) == 0) sred[tid >> 6] = val;
  __syncthreads();
  if (tid == 0) atomicAdd(out, sred[0] + sred[1] + sred[2] + sred[3]);
}

extern "C" void kernel_launch(void* const* d_in, const int* in_sizes, int n_in,
                              void* d_out, int out_size, void* d_ws, size_t ws_size,
                              hipStream_t stream) {
  const float* x  = (const float*)d_in[0];
  const float* y  = (const float*)d_in[1];
  const float* W1 = (const float*)d_in[2];
  const float* b1 = (const float*)d_in[3];
  const float* W2 = (const float*)d_in[4];
  const float* b2 = (const float*)d_in[5];
  u32* wsu = (u32*)d_ws;

  hipLaunchKernelGGL(k0_pack, dim3(192), dim3(256), 0, stream, x, y, W1, W2, wsu,
                     (float*)d_out);
  hipLaunchKernelGGL(k1_pre, dim3(512), dim3(256), 0, stream, wsu, b1);
  hipLaunchKernelGGL(k2_main, dim3(256), dim3(256), 0, stream, wsu, b2,
                     (float*)d_out);
}

// Round 6
// 95.459 us; speedup vs baseline: 1.3989x; 1.3989x over previous
//
#include <hip/hip_runtime.h>

typedef _Float16 h2 __attribute__((ext_vector_type(2)));
typedef unsigned int u32;

// Workspace layout (bytes).
#define OFF_W2H  0xA0000u   // half2[128]       W2 h-pair packed
#define OFF_A2   0x100000u  // half2 TILED: [32 slab][32 row][128 hh]  (pre_x)
#define OFF_C2   0x180000u  // same tiling      (pre_y + b1)

__device__ __forceinline__ u32 pack2(float a, float b) {
  h2 v; v.x = (_Float16)a; v.y = (_Float16)b;
  return __builtin_bit_cast(u32, v);
}
__device__ __forceinline__ h2 as_h2(u32 u) { return __builtin_bit_cast(h2, u); }

__device__ __forceinline__ h2 cvt2(float a, float b) {
#if __has_builtin(__builtin_amdgcn_cvt_pkrtz)
  return __builtin_bit_cast(h2, __builtin_amdgcn_cvt_pkrtz(a, b));  // v_cvt_pkrtz_f16_f32
#else
  h2 v; v.x = (_Float16)a; v.y = (_Float16)b; return v;
#endif
}
__device__ __forceinline__ float fdot2(h2 a, h2 b, float c) {
#if __has_builtin(__builtin_amdgcn_fdot2)
  return __builtin_amdgcn_fdot2(a, b, c, false);
#else
  return (float)a.x * (float)b.x + (float)a.y * (float)b.y + c;
#endif
}
__device__ __forceinline__ h2 relu2(h2 t) {
  h2 z; z.x = (_Float16)0.0f; z.y = (_Float16)0.0f;
  return __builtin_elementwise_max(t, z);       // v_pk_max_f16
}

// K1: pre_x -> A2, pre_y + b1 -> C2, straight from raw fp32 inputs
// (in-register cvt_pkrtz; no packing pre-pass). Block 256: W2 pack + out init.
// Layout (u32 = half2 of h-pair): idx = (row>>5)*4096 + (row&31)*128 + hh.
__global__ __launch_bounds__(256) void k1_pre(const float* __restrict__ x,
                                              const float* __restrict__ y,
                                              const float* __restrict__ W1,
                                              const float* __restrict__ b1,
                                              const float* __restrict__ W2,
                                              u32* __restrict__ wsu,
                                              float* __restrict__ out) {
  const int b = blockIdx.x, tid = threadIdx.x;
  if (b == 256) {                               // W2 h-pair pack + accumulator init
    if (tid < 128) wsu[(OFF_W2H >> 2) + tid] = pack2(W2[2 * tid], W2[2 * tid + 1]);
    if (tid == 128) out[0] = 0.0f;              // d_out is poisoned by harness
    return;
  }
  const int mat = b >> 7;                       // 0: x->A2, 1: y->C2
  const int idx = b & 127, ht = idx & 7, rt = idx >> 3;  // 16 hh x 64 rows per block
  const int tx = tid & 15, ty = tid >> 4;       // hh lane, row group
  const int h0 = ht * 32 + tx * 2;              // this thread's two h columns
  const int r0 = rt * 64 + ty * 4;              // this thread's four rows
  const float* src = (mat ? y : x) + r0 * 128;
  const float* w1p = W1 + (mat ? 128 * 256 : 0) + h0;
  u32* dst = wsu + ((mat ? OFF_C2 : OFF_A2) >> 2) + ht * 16 + tx;

  float acc0[4], acc1[4];
  float bx = 0.0f, by = 0.0f;
  if (mat) { const float2 bv = *(const float2*)(b1 + h0); bx = bv.x; by = bv.y; }
#pragma unroll
  for (int i = 0; i < 4; ++i) { acc0[i] = bx; acc1[i] = by; }

#pragma unroll 4
  for (int kk = 0; kk < 64; ++kk) {
    // W1 rows 2kk,2kk+1 at cols h0,h0+1 -> coalesced 8B loads (lane=tx)
    const float2 wA = *(const float2*)(w1p + (2 * kk) * 256);
    const float2 wB = *(const float2*)(w1p + (2 * kk + 1) * 256);
    const h2 w0 = cvt2(wA.x, wB.x);             // h2(W1[2kk][h0], W1[2kk+1][h0])
    const h2 w1h = cvt2(wA.y, wB.y);
#pragma unroll
    for (int i = 0; i < 4; ++i) {               // x[r, 2kk:2kk+2]: 16-lane broadcast
      const float2 xv = *(const float2*)(src + i * 128 + 2 * kk);
      const h2 xh = cvt2(xv.x, xv.y);
      acc0[i] = fdot2(xh, w0, acc0[i]);
      acc1[i] = fdot2(xh, w1h, acc1[i]);
    }
  }
#pragma unroll
  for (int i = 0; i < 4; ++i) {
    const int R = r0 + i;
    dst[(R >> 5) * 4096 + (R & 31) * 128] = pack2(acc0[i], acc1[i]);
  }
}

// K2: main N^2 kernel. 256 blocks of 64x64 rows; 4x4 rows/thread (16 acc).
// Per 4-hh group/wave: 8 ds_read_b128 (LDS 384 cyc/CU) vs 192 VALU (384
// cyc/SIMD) -> balanced at the ~5.1us VALU floor. NO runtime-indexed local
// arrays (R4's ring spilled to scratch: 79MB HBM writes). W2 via uniform load.
__global__ __launch_bounds__(256, 1) void k2_main(const u32* __restrict__ wsu,
                                                  const float* __restrict__ B2,
                                                  float* __restrict__ out) {
  const int bi = blockIdx.x >> 4, bj = blockIdx.x & 15;
  const int tid = threadIdx.x;
  const int tx = tid & 15, ty = tid >> 4;       // j-group, i-group (4 rows each)

  __shared__ uint4 sA4[64 * 32];                // [row][quad ^ ((row>>2)&7)]
  __shared__ uint4 sC4[64 * 32];
  __shared__ float sred[4];

  {                                             // stage 64KB once; 8 lanes/row ->
    const u32* gA = wsu + (OFF_A2 >> 2) + bj * 8192;   // quads 0..7 -> all 32 banks
    const u32* gC = wsu + (OFF_C2 >> 2) + bi * 8192;   // (conflict-free writes)
    const int j = tid >> 3, t8 = tid & 7;
#pragma unroll
    for (int half = 0; half < 2; ++half) {
      const int row = j + 32 * half;
      const int sw = (row >> 2) & 7;
#pragma unroll
      for (int m = 0; m < 4; ++m) {
        const int q = t8 + 8 * m;
        sA4[row * 32 + (q ^ sw)] = *(const uint4*)(gA + row * 128 + q * 4);
        sC4[row * 32 + (q ^ sw)] = *(const uint4*)(gC + row * 128 + q * 4);
      }
    }
  }
  __syncthreads();

  const uint4* pA = sA4 + (tx * 4) * 32;        // rows 4tx..4tx+3
  const uint4* pC = sC4 + (ty * 4) * 32;        // rows 4ty..4ty+3
  const uint4* pW = (const uint4*)(wsu + (OFF_W2H >> 2));  // uniform
  const int swzA = tx & 7, swzC = ty & 7;

  float acc[16];
#pragma unroll
  for (int p = 0; p < 16; ++p) acc[p] = 0.0f;

#pragma unroll 2
  for (int g = 0; g < 32; ++g) {                // 4 hh per step
    const uint4 av0 = pA[0 * 32 + (g ^ swzA)];
    const uint4 av1 = pA[1 * 32 + (g ^ swzA)];
    const uint4 av2 = pA[2 * 32 + (g ^ swzA)];
    const uint4 av3 = pA[3 * 32 + (g ^ swzA)];
    const uint4 cv0 = pC[0 * 32 + (g ^ swzC)];
    const uint4 cv1 = pC[1 * 32 + (g ^ swzC)];
    const uint4 cv2 = pC[2 * 32 + (g ^ swzC)];
    const uint4 cv3 = pC[3 * 32 + (g ^ swzC)];
    const uint4 wv = pW[g];
    const u32 ww[4] = {wv.x, wv.y, wv.z, wv.w};
    const u32 aa[4][4] = {{av0.x, av0.y, av0.z, av0.w},
                          {av1.x, av1.y, av1.z, av1.w},
                          {av2.x, av2.y, av2.z, av2.w},
                          {av3.x, av3.y, av3.z, av3.w}};
    const u32 cc[4][4] = {{cv0.x, cv0.y, cv0.z, cv0.w},
                          {cv1.x, cv1.y, cv1.z, cv1.w},
                          {cv2.x, cv2.y, cv2.z, cv2.w},
                          {cv3.x, cv3.y, cv3.z, cv3.w}};
#pragma unroll
    for (int m = 0; m < 4; ++m) {               // all indices compile-time ->
      const h2 w = as_h2(ww[m]);                // everything stays in VGPRs
#pragma unroll
      for (int ii = 0; ii < 4; ++ii) {
        const h2 ci = as_h2(cc[ii][m]);
#pragma unroll
        for (int jj = 0; jj < 4; ++jj) {
          acc[ii * 4 + jj] = fdot2(relu2(as_h2(aa[jj][m]) + ci), w, acc[ii * 4 + jj]);
        }
      }
    }
  }

  // result = (1/n) sum_i (T1_ii + 1) - (1/n^2) sum_ij exp(T1_ij),
  // T1_ij = d_ij + b2 - 1.  acc[] holds d_ij.
  const float b2 = B2[0];
  float val = 0.0f;
#pragma unroll
  for (int p = 0; p < 16; ++p) val += __expf(acc[p] + (b2 - 1.0f));
  val *= -1.0f / 1048576.0f;
  if (bi == bj && tx == ty) {                   // diag: local i==j -> acc[c*5]
    float d = 0.0f;
#pragma unroll
    for (int c = 0; c < 4; ++c) d += acc[c * 5];
    val += (d + 4.0f * b2) * (1.0f / 1024.0f);
  }
#pragma unroll
  for (int off = 32; off > 0; off >>= 1) val += __shfl_down(val, off, 64);
  if ((tid & 63) == 0) sred[tid >> 6] = val;
  __syncthreads();
  if (tid == 0) atomicAdd(out, sred[0] + sred[1] + sred[2] + sred[3]);
}

extern "C" void kernel_launch(void* const* d_in, const int* in_sizes, int n_in,
                              void* d_out, int out_size, void* d_ws, size_t ws_size,
                              hipStream_t stream) {
  const float* x  = (const float*)d_in[0];
  const float* y  = (const float*)d_in[1];
  const float* W1 = (const float*)d_in[2];
  const float* b1 = (const float*)d_in[3];
  const float* W2 = (const float*)d_in[4];
  const float* b2 = (const float*)d_in[5];
  u32* wsu = (u32*)d_ws;

  hipLaunchKernelGGL(k1_pre, dim3(257), dim3(256), 0, stream, x, y, W1, b1, W2,
                     wsu, (float*)d_out);
  hipLaunchKernelGGL(k2_main, dim3(256), dim3(256), 0, stream, wsu, b2,
                     (float*)d_out);
}